// Round 1
// baseline (144.995 us; speedup 1.0000x reference)
//
#include <hip/hip_runtime.h>

// Problem constants (match reference)
constexpr int   B_ = 8;
constexpr int   T_ = 100;
constexpr int   NPAIRS = B_ * T_;      // 800
constexpr int   N_ = 100000;
constexpr float MARGIN_ = 0.1f;
constexpr float THRESHOLD_ = 0.5f;
constexpr float BIG_ = 1000000000.0f;

// Workspace layout (bytes)
constexpr size_t PAIRS_OFF  = 0;                         // float4[1024] (rx,ry,rz,r2)
constexpr size_t BOUNDS_OFF = 16384;                     // float[48]: l[8][3], u[8][3]
constexpr size_t MEANS_OFF  = 16640;                     // float4[N]  (mx,my,mz,maxrad+MARGIN)
constexpr size_t MASK_OFF   = MEANS_OFF + (size_t)N_ * 16; // uint[N] inside-bitmask (8 bits)
constexpr size_t KEYS_OFF   = MASK_OFF + (size_t)N_ * 4;   // uint[1024] orderable min-keys
// total ~2.02 MB of d_ws

// Map float -> uint such that uint order == float order (handles negatives).
__device__ __forceinline__ unsigned fkey(float f) {
    unsigned u = __float_as_uint(f);
    return (u & 0x80000000u) ? ~u : (u | 0x80000000u);
}

// K1: pairs (retrajs + r2), per-b AABB bounds, init min-keys. 1 block x 1024.
__global__ void k_prep(const float* __restrict__ outputs,
                       const float* __restrict__ c2ws,
                       const float* __restrict__ ss,
                       char* ws) {
    __shared__ float re_s[NPAIRS * 3];
    int tid = threadIdx.x;
    float4*   pairs  = (float4*)(ws + PAIRS_OFF);
    float*    bounds = (float*)(ws + BOUNDS_OFF);
    unsigned* keys   = (unsigned*)(ws + KEYS_OFF);

    if (tid < NPAIRS) {
        int b = tid / T_;
        float s = ss[b];
        const float* o = outputs + tid * 3;
        float o0 = o[0], o1 = o[1], o2 = o[2];
        const float* c = c2ws + b * 16;
        float re[3];
#pragma unroll
        for (int e = 0; e < 3; e++) {
            // retrajs[b,t,e] = sum_d o[d]*c2ws[b,e,d]*ss[b] + c2ws[b,e,3]
            re[e] = (o0 * c[e * 4 + 0] + o1 * c[e * 4 + 1] + o2 * c[e * 4 + 2]) * s + c[e * 4 + 3];
            re_s[tid * 3 + e] = re[e];
        }
        pairs[tid] = make_float4(re[0], re[1], re[2],
                                 re[0] * re[0] + re[1] * re[1] + re[2] * re[2]);
    }
    // re-init keys EVERY call (ws is re-poisoned before each timed launch)
    keys[tid] = __float_as_uint(BIG_) | 0x80000000u;  // fkey(BIG)

    __syncthreads();
    if (tid < 24) {
        int b = tid / 3, e = tid - b * 3;
        float mx = -3.4e38f, mn = 3.4e38f;
        for (int t = 0; t < T_; t++) {
            float v = re_s[(b * T_ + t) * 3 + e];
            mx = fmaxf(mx, v);
            mn = fminf(mn, v);
        }
        float thres = THRESHOLD_ * ss[0];  // reference uses scene_scales[0] for all b
        bounds[b * 3 + e]      = mn - thres;  // lvals
        bounds[24 + b * 3 + e] = mx + thres;  // uvals
    }
}

// K2: pack per-splat float4 + inside bitmask.
__global__ void k_means(const float* __restrict__ means,
                        const float* __restrict__ scales,
                        char* ws) {
    int n = blockIdx.x * blockDim.x + threadIdx.x;
    if (n >= N_) return;
    const float* bounds = (const float*)(ws + BOUNDS_OFF);
    float4*   pm    = (float4*)(ws + MEANS_OFF);
    unsigned* pmask = (unsigned*)(ws + MASK_OFF);

    float mx = means[n * 3 + 0], my = means[n * 3 + 1], mz = means[n * 3 + 2];
    float msr = fmaxf(fmaxf(scales[n * 3 + 0], scales[n * 3 + 1]), scales[n * 3 + 2]) + MARGIN_;
    unsigned mask = 0;
#pragma unroll
    for (int b = 0; b < 8; b++) {
        bool in = (mx >= bounds[b * 3 + 0]) & (mx <= bounds[24 + b * 3 + 0]) &
                  (my >= bounds[b * 3 + 1]) & (my <= bounds[24 + b * 3 + 1]) &
                  (mz >= bounds[b * 3 + 2]) & (mz <= bounds[24 + b * 3 + 2]);
        mask |= (unsigned)in << b;
    }
    pm[n]    = make_float4(mx, my, mz, msr);
    pmask[n] = mask;
}

// K3: main interaction loop. Each thread owns 4 pairs (registers); block stages
// NCHUNK splats in LDS; broadcast reads (all lanes same address -> conflict-free).
constexpr int NCHUNK = 128;
__global__ __launch_bounds__(256) void k_main(const char* __restrict__ wsc, char* ws) {
    __shared__ float4   sm[NCHUNK];
    __shared__ unsigned smk[NCHUNK];
    int tid = threadIdx.x;
    const float4*   pairs = (const float4*)(wsc + PAIRS_OFF);
    const float4*   pm    = (const float4*)(wsc + MEANS_OFF);
    const unsigned* pmask = (const unsigned*)(wsc + MASK_OFF);
    unsigned* keys = (unsigned*)(ws + KEYS_OFF);

    int n0 = blockIdx.x * NCHUNK;

    float4   pr[4];
    unsigned pbit[4];
    int      pidx[4];
#pragma unroll
    for (int j = 0; j < 4; j++) {
        int p = tid + j * 256;
        pidx[j] = p;
        if (p < NPAIRS) {
            pr[j]   = pairs[p];
            pbit[j] = 1u << (p / T_);
        } else {
            pr[j]   = make_float4(0.f, 0.f, 0.f, 0.f);
            pbit[j] = 0u;   // never "inside" -> cand stays BIG
        }
    }

    if (tid < NCHUNK) {
        int n = n0 + tid;
        if (n < N_) {
            sm[tid]  = pm[n];
            smk[tid] = pmask[n];
        } else {
            sm[tid]  = make_float4(0.f, 0.f, 0.f, 1.f);
            smk[tid] = 0u;
        }
    }
    __syncthreads();

    float mnv[4] = {BIG_, BIG_, BIG_, BIG_};
    int cnt = min(NCHUNK, N_ - n0);
    for (int i = 0; i < cnt; i++) {
        float4  m = sm[i];
        unsigned k = smk[i];
        float m2 = fmaf(m.x, m.x, fmaf(m.y, m.y, m.z * m.z));
#pragma unroll
        for (int j = 0; j < 4; j++) {
            float c  = fmaf(pr[j].x, m.x, fmaf(pr[j].y, m.y, pr[j].z * m.z));
            float d2 = fmaf(-2.f, c, pr[j].w + m2);
            float res = __builtin_sqrtf(fmaxf(d2, 0.f)) - m.w;  // m.w = maxrad+MARGIN
            float cand = (k & pbit[j]) ? res : BIG_;
            mnv[j] = fminf(mnv[j], cand);
        }
    }

#pragma unroll
    for (int j = 0; j < 4; j++) {
        if (pidx[j] < NPAIRS) atomicMin(&keys[pidx[j]], fkey(mnv[j]));
    }
}

// K4: decode keys, sum relu(-min)/800 -> scalar out.
__global__ void k_final(const char* __restrict__ wsc, float* __restrict__ out) {
    const unsigned* keys = (const unsigned*)(wsc + KEYS_OFF);
    int tid = threadIdx.x;
    float acc = 0.f;
    for (int p = tid; p < NPAIRS; p += 256) {
        unsigned k = keys[p];
        unsigned u = (k & 0x80000000u) ? (k ^ 0x80000000u) : ~k;
        float f = __uint_as_float(u);
        acc += fmaxf(0.f, -f);
    }
#pragma unroll
    for (int off = 32; off; off >>= 1) acc += __shfl_down(acc, off, 64);
    __shared__ float wsum[4];
    if ((tid & 63) == 0) wsum[tid >> 6] = acc;
    __syncthreads();
    if (tid == 0) out[0] = (wsum[0] + wsum[1] + wsum[2] + wsum[3]) / (float)(B_ * T_);
}

extern "C" void kernel_launch(void* const* d_in, const int* in_sizes, int n_in,
                              void* d_out, int out_size, void* d_ws, size_t ws_size,
                              hipStream_t stream) {
    const float* outputs = (const float*)d_in[0];   // (B,T,3)
    const float* c2ws    = (const float*)d_in[1];   // (B,4,4)
    const float* ss      = (const float*)d_in[2];   // (B,)
    const float* means   = (const float*)d_in[3];   // (N,3)
    const float* scales  = (const float*)d_in[4];   // (N,3)
    float* out = (float*)d_out;
    char*  ws  = (char*)d_ws;

    hipLaunchKernelGGL(k_prep, dim3(1), dim3(1024), 0, stream, outputs, c2ws, ss, ws);
    hipLaunchKernelGGL(k_means, dim3((N_ + 255) / 256), dim3(256), 0, stream, means, scales, ws);
    hipLaunchKernelGGL(k_main, dim3((N_ + NCHUNK - 1) / NCHUNK), dim3(256), 0, stream,
                       (const char*)ws, ws);
    hipLaunchKernelGGL(k_final, dim3(1), dim3(256), 0, stream, (const char*)ws, out);
}

// Round 5
// 101.544 us; speedup vs baseline: 1.4279x; 1.4279x over previous
//
#include <hip/hip_runtime.h>

// Problem constants (match reference)
constexpr int   B_ = 8;
constexpr int   T_ = 100;
constexpr int   NPAIRS = B_ * T_;      // 800
constexpr int   N_ = 100000;
constexpr float MARGIN_ = 0.1f;
constexpr float THRESHOLD_ = 0.5f;
constexpr float BIG_ = 1000000000.0f;

// Workspace layout (bytes) — ~4.83 MB total
constexpr size_t PM_OFF     = 0;                          // float4[N]: (mx,my,mz,0)
constexpr size_t MSR_OFF    = PM_OFF + (size_t)N_ * 16;   // float[N][8]: msr_eff per batch
constexpr size_t KEYS_OFF   = MSR_OFF + (size_t)N_ * 32;  // uint[800] orderable min-keys
constexpr size_t PAIRS_OFF  = KEYS_OFF + 4096;            // float4[800]: (rx,ry,rz,0)
constexpr size_t BOUNDS_OFF = PAIRS_OFF + 16384;          // float[48]: l[8][3], u[8][3]

// fast hardware sqrt: single v_sqrt_f32
__device__ __forceinline__ float fsqrt(float x) { return __builtin_amdgcn_sqrtf(x); }

// Map float -> uint such that uint order == float order (handles negatives).
__device__ __forceinline__ unsigned fkey(float f) {
    unsigned u = __float_as_uint(f);
    return (u & 0x80000000u) ? ~u : (u | 0x80000000u);
}

// K1: pairs (retrajs), per-b AABB bounds, init min-keys. 1 block x 1024.
__global__ void k_prep(const float* __restrict__ outputs,
                       const float* __restrict__ c2ws,
                       const float* __restrict__ ss,
                       char* ws) {
    __shared__ float re_s[NPAIRS * 3];
    int tid = threadIdx.x;
    float4*   pairs  = (float4*)(ws + PAIRS_OFF);
    float*    bounds = (float*)(ws + BOUNDS_OFF);
    unsigned* keys   = (unsigned*)(ws + KEYS_OFF);

    if (tid < NPAIRS) {
        int b = tid / T_;
        float s = ss[b];
        const float* o = outputs + tid * 3;
        float o0 = o[0], o1 = o[1], o2 = o[2];
        const float* c = c2ws + b * 16;
        float re[3];
#pragma unroll
        for (int e = 0; e < 3; e++) {
            re[e] = (o0 * c[e * 4 + 0] + o1 * c[e * 4 + 1] + o2 * c[e * 4 + 2]) * s + c[e * 4 + 3];
            re_s[tid * 3 + e] = re[e];
        }
        pairs[tid] = make_float4(re[0], re[1], re[2], 0.f);
        // re-init keys EVERY call (ws is re-poisoned before each timed launch)
        keys[tid] = fkey(BIG_);
    }

    __syncthreads();
    if (tid < 24) {
        int b = tid / 3, e = tid - b * 3;
        float mx = -3.4e38f, mn = 3.4e38f;
        for (int t = 0; t < T_; t++) {
            float v = re_s[(b * T_ + t) * 3 + e];
            mx = fmaxf(mx, v);
            mn = fminf(mn, v);
        }
        float thres = THRESHOLD_ * ss[0];  // reference uses scene_scales[0] for all b
        bounds[b * 3 + e]      = mn - thres;  // lvals
        bounds[24 + b * 3 + e] = mx + thres;  // uvals
    }
}

// K2: per-splat packed data: float4 (mx,my,mz,0) + 8 x msr_eff
//     msr_eff[b] = inside_b ? (maxrad + MARGIN) : -BIG  (so dist - msr_eff >= BIG when excluded)
__global__ void k_means(const float* __restrict__ means,
                        const float* __restrict__ scales,
                        char* ws) {
    int n = blockIdx.x * blockDim.x + threadIdx.x;
    if (n >= N_) return;
    const float* bounds = (const float*)(ws + BOUNDS_OFF);
    float4* pm   = (float4*)(ws + PM_OFF);
    float4* msrv = (float4*)(ws + MSR_OFF);

    float mx = means[n * 3 + 0], my = means[n * 3 + 1], mz = means[n * 3 + 2];
    float msr = fmaxf(fmaxf(scales[n * 3 + 0], scales[n * 3 + 1]), scales[n * 3 + 2]) + MARGIN_;
    float eff[8];
#pragma unroll
    for (int b = 0; b < 8; b++) {
        bool in = (mx >= bounds[b * 3 + 0]) & (mx <= bounds[24 + b * 3 + 0]) &
                  (my >= bounds[b * 3 + 1]) & (my <= bounds[24 + b * 3 + 1]) &
                  (mz >= bounds[b * 3 + 2]) & (mz <= bounds[24 + b * 3 + 2]);
        eff[b] = in ? msr : -BIG_;
    }
    pm[n] = make_float4(mx, my, mz, 0.f);
    msrv[n * 2 + 0] = make_float4(eff[0], eff[1], eff[2], eff[3]);
    msrv[n * 2 + 1] = make_float4(eff[4], eff[5], eff[6], eff[7]);
}

// K3: main interaction loop. 1021 blocks x 256 threads; each block owns PER=98
// splats (staged in LDS), each thread owns pairs {tid, tid+256, tid+512} as
// NAMED SCALARS (no arrays -> no scratch); lanes 0..31 additionally own pair
// 768+tid in a separate tail loop (96% lane utilization).
constexpr int PER = 98;
constexpr int NBLK = (N_ + PER - 1) / PER;  // 1021

__global__ __launch_bounds__(256) void k_main(const char* __restrict__ wsc, char* ws) {
    __shared__ float4 pm_s[PER];
    __shared__ float  msr_s[PER * 8];
    int tid = threadIdx.x;
    const float4* pmg   = (const float4*)(wsc + PM_OFF);
    const float4* msrg  = (const float4*)(wsc + MSR_OFF);
    const float4* pairs = (const float4*)(wsc + PAIRS_OFF);
    unsigned* keys = (unsigned*)(ws + KEYS_OFF);

    int base = blockIdx.x * PER;
    int cnt  = min(PER, N_ - base);

    // stage splats
    if (tid < cnt) pm_s[tid] = pmg[base + tid];
    if (tid < 2 * cnt) ((float4*)msr_s)[tid] = msrg[2 * base + tid];

    // per-thread pairs as named scalars
    int p0 = tid, p1 = tid + 256, p2 = tid + 512;
    float4 q0 = pairs[p0];
    float4 q1 = pairs[p1];
    float4 q2 = pairs[p2];
    int b0 = p0 / T_, b1 = p1 / T_, b2 = p2 / T_;

    __syncthreads();

    float mn0 = BIG_, mn1 = BIG_, mn2 = BIG_;
    const float*  mp = msr_s;
    const float4* sp = pm_s;
    for (int i = 0; i < cnt; i++) {
        float4 m = sp[i];
        float e0 = mp[b0], e1 = mp[b1], e2 = mp[b2];
        mp += 8;
        float dx, dy, dz, d2;
        dx = q0.x - m.x; dy = q0.y - m.y; dz = q0.z - m.z;
        d2 = fmaf(dz, dz, fmaf(dy, dy, dx * dx));
        mn0 = fminf(mn0, fsqrt(d2) - e0);
        dx = q1.x - m.x; dy = q1.y - m.y; dz = q1.z - m.z;
        d2 = fmaf(dz, dz, fmaf(dy, dy, dx * dx));
        mn1 = fminf(mn1, fsqrt(d2) - e1);
        dx = q2.x - m.x; dy = q2.y - m.y; dz = q2.z - m.z;
        d2 = fmaf(dz, dz, fmaf(dy, dy, dx * dx));
        mn2 = fminf(mn2, fsqrt(d2) - e2);
    }
    atomicMin(&keys[p0], fkey(mn0));
    atomicMin(&keys[p1], fkey(mn1));
    atomicMin(&keys[p2], fkey(mn2));

    // tail: pairs 768..799 handled by lanes 0..31 of wave 0 (other waves skip via execz)
    if (tid < 32) {
        int p3 = 768 + tid;
        float4 q3 = pairs[p3];
        int b3 = p3 / T_;
        float mn3 = BIG_;
        const float* mp3 = msr_s;
        for (int i = 0; i < cnt; i++) {
            float4 m = pm_s[i];
            float e3 = mp3[b3];
            mp3 += 8;
            float dx = q3.x - m.x, dy = q3.y - m.y, dz = q3.z - m.z;
            float d2 = fmaf(dz, dz, fmaf(dy, dy, dx * dx));
            mn3 = fminf(mn3, fsqrt(d2) - e3);
        }
        atomicMin(&keys[p3], fkey(mn3));
    }
}

// K4: decode keys, sum relu(-min)/800 -> scalar out.
__global__ void k_final(const char* __restrict__ wsc, float* __restrict__ out) {
    const unsigned* keys = (const unsigned*)(wsc + KEYS_OFF);
    int tid = threadIdx.x;
    float acc = 0.f;
    for (int p = tid; p < NPAIRS; p += 256) {
        unsigned k = keys[p];
        unsigned u = (k & 0x80000000u) ? (k ^ 0x80000000u) : ~k;
        float f = __uint_as_float(u);
        acc += fmaxf(0.f, -f);
    }
#pragma unroll
    for (int off = 32; off; off >>= 1) acc += __shfl_down(acc, off, 64);
    __shared__ float wsum[4];
    if ((tid & 63) == 0) wsum[tid >> 6] = acc;
    __syncthreads();
    if (tid == 0) out[0] = (wsum[0] + wsum[1] + wsum[2] + wsum[3]) / (float)(B_ * T_);
}

extern "C" void kernel_launch(void* const* d_in, const int* in_sizes, int n_in,
                              void* d_out, int out_size, void* d_ws, size_t ws_size,
                              hipStream_t stream) {
    const float* outputs = (const float*)d_in[0];   // (B,T,3)
    const float* c2ws    = (const float*)d_in[1];   // (B,4,4)
    const float* ss      = (const float*)d_in[2];   // (B,)
    const float* means   = (const float*)d_in[3];   // (N,3)
    const float* scales  = (const float*)d_in[4];   // (N,3)
    float* out = (float*)d_out;
    char*  ws  = (char*)d_ws;

    hipLaunchKernelGGL(k_prep, dim3(1), dim3(1024), 0, stream, outputs, c2ws, ss, ws);
    hipLaunchKernelGGL(k_means, dim3((N_ + 255) / 256), dim3(256), 0, stream, means, scales, ws);
    hipLaunchKernelGGL(k_main, dim3(NBLK), dim3(256), 0, stream, (const char*)ws, ws);
    hipLaunchKernelGGL(k_final, dim3(1), dim3(256), 0, stream, (const char*)ws, out);
}